// Round 1
// 1048.033 us; speedup vs baseline: 1.1457x; 1.1457x over previous
//
#include <hip/hip_runtime.h>

#define B_ 1024
#define S_ 128
#define E_ 256
#define H_ 8
#define D_ 64
#define HD_ 512

typedef short s16x8 __attribute__((ext_vector_type(8)));   // 8 bf16 (guide §3)
typedef float f32x4 __attribute__((ext_vector_type(4)));
typedef unsigned int u32x4 __attribute__((ext_vector_type(4)));
typedef unsigned short u16;
typedef unsigned int u32;

struct U16x8 { u16 v[8]; };

__device__ __forceinline__ u16 f2bf(float f) {
  u32 u = __float_as_uint(f);
  u += 0x7FFFu + ((u >> 16) & 1u);   // round-to-nearest-even
  return (u16)(u >> 16);
}

// pack two f32 -> one u32 of 2x bf16 (lo = s0, hi = s1); no builtin on gfx950
__device__ __forceinline__ u32 cvtpk_bf16(float lo, float hi) {
  u32 r;
  asm("v_cvt_pk_bf16_f32 %0, %1, %2" : "=v"(r) : "v"(lo), "v"(hi));
  return r;
}

// ---------------------------------------------------------------------------
// Dtype probe: decide whether inputs are packed bf16 or float32.
// flag[0] = 1 (bf16) or 0 (f32), recomputed every launch (graph-safe).
// ---------------------------------------------------------------------------
__global__ __launch_bounds__(256) void probe_dtype(const u32* __restrict__ x,
                                                   u32* __restrict__ flag) {
  __shared__ int cnt;
  if (threadIdx.x == 0) cnt = 0;
  __syncthreads();
  u32 w = x[threadIdx.x];
  u32 e = (w >> 7) & 0xFFu;
  if (e > 96u && e < 160u) atomicAdd(&cnt, 1);
  __syncthreads();
  if (threadIdx.x == 0) flag[0] = (cnt > 128) ? 1u : 0u;
}

// ---------------------------------------------------------------------------
// Repack the four (E x HD) weights into bf16 MFMA B-fragment order:
// WF[(((w*8+h)*8+ks)*4+tc)*64+lane][j] = W_w[ks*32+(lane>>4)*8+j][h*64+tc*16+(lane&15)]
// ---------------------------------------------------------------------------
__global__ __launch_bounds__(256) void repack_w(
    const void* __restrict__ wqv, const void* __restrict__ wkv,
    const void* __restrict__ wvv, const void* __restrict__ wrv,
    const u32* __restrict__ flag, u16* __restrict__ wf) {
  bool isbf = (flag[0] != 0u);
  int t = blockIdx.x * 256 + threadIdx.x;   // 65536 threads total
  int lane = t & 63;
  int tc   = (t >> 6) & 3;
  int ks   = (t >> 8) & 7;
  int h    = (t >> 11) & 7;
  int w    = (t >> 14) & 3;
  const void* srcv = (w == 0) ? wqv : (w == 1) ? wkv : (w == 2) ? wvv : wrv;
  int n  = h * D_ + tc * 16 + (lane & 15);
  int e0 = ks * 32 + (lane >> 4) * 8;
  U16x8 tmp;
  if (isbf) {
    const u16* s = (const u16*)srcv;
#pragma unroll
    for (int j = 0; j < 8; ++j) tmp.v[j] = s[(e0 + j) * HD_ + n];
  } else {
    const float* s = (const float*)srcv;
#pragma unroll
    for (int j = 0; j < 8; ++j) tmp.v[j] = f2bf(s[(e0 + j) * HD_ + n]);
  }
  *(u32x4*)(wf + (size_t)t * 8) = *(const u32x4*)tmp.v;
}

// Projection via repacked fragments: one dwordx4 per B-frag.
__device__ __forceinline__ void proj4_wf(const u32x4* __restrict__ wf4lane, int base8,
                                         const s16x8 xfrag[8], f32x4 acc[4]) {
#pragma unroll
  for (int tc = 0; tc < 4; ++tc) acc[tc] = (f32x4){0.f, 0.f, 0.f, 0.f};
#pragma unroll
  for (int ks = 0; ks < 8; ++ks) {
#pragma unroll
    for (int tc = 0; tc < 4; ++tc) {
      u32x4 raw = wf4lane[((base8 * 8 + ks) * 4 + tc) * 64];
      s16x8 bfr = *(const s16x8*)&raw;
      acc[tc] = __builtin_amdgcn_mfma_f32_16x16x32_bf16(xfrag[ks], bfr, acc[tc], 0, 0, 0);
    }
  }
}

// Fallback (ws too small for WF): gather B-frags from the original layout.
__device__ __forceinline__ void proj4_direct(const void* __restrict__ srcv, bool isbf,
                                             int h, int lane, const s16x8 xfrag[8],
                                             f32x4 acc[4]) {
#pragma unroll
  for (int tc = 0; tc < 4; ++tc) acc[tc] = (f32x4){0.f, 0.f, 0.f, 0.f};
  int e8 = (lane >> 4) * 8;
  int nc = h * D_ + (lane & 15);
#pragma unroll
  for (int ks = 0; ks < 8; ++ks) {
#pragma unroll
    for (int tc = 0; tc < 4; ++tc) {
      U16x8 tmp;
      if (isbf) {
        const u16* s = (const u16*)srcv;
#pragma unroll
        for (int j = 0; j < 8; ++j) tmp.v[j] = s[(ks * 32 + e8 + j) * HD_ + nc + tc * 16];
      } else {
        const float* s = (const float*)srcv;
#pragma unroll
        for (int j = 0; j < 8; ++j) tmp.v[j] = f2bf(s[(ks * 32 + e8 + j) * HD_ + nc + tc * 16]);
      }
      s16x8 bfr = *(const s16x8*)tmp.v;
      acc[tc] = __builtin_amdgcn_mfma_f32_16x16x32_bf16(xfrag[ks], bfr, acc[tc], 0, 0, 0);
    }
  }
}

// Scatter projection C-frags (row=quad*4+r, col=tc*16+col) into A/B-frag-major
// LDS layout — same index formula for Q and K.
__device__ __forceinline__ void scatter_qk(u16* dst, int w, int quad, int col,
                                           const f32x4 acc[4]) {
#pragma unroll
  for (int tc = 0; tc < 4; ++tc) {
    int ks2 = tc >> 1;
    int q2  = (tc & 1) * 2 + (col >> 3);
#pragma unroll
    for (int r = 0; r < 4; ++r)
      dst[(((w * 2 + ks2) * 64) + q2 * 16 + quad * 4 + r) * 8 + (col & 7)] =
          f2bf(acc[tc][r]);
  }
}

// V goes to B-frag-major for O = P@V (k = s', n = d).
__device__ __forceinline__ void scatter_v(u16* Vf, int w, int quad, int col,
                                          const f32x4 acc[4]) {
#pragma unroll
  for (int tc = 0; tc < 4; ++tc)
#pragma unroll
    for (int r = 0; r < 4; ++r) {
      int srow = quad * 4 + r;
      int q2   = (w & 1) * 2 + (srow >> 3);
      Vf[((((w >> 1) * 4 + tc) * 64) + q2 * 16 + col) * 8 + (srow & 7)] =
          f2bf(acc[tc][r]);
    }
}

// ---------------------------------------------------------------------------
// Fused MHA: one workgroup per batch, 8 waves, head loop inside.
// LDS (48 KiB): Qf 16K | Kf 16K | Vf 16K   -> 3 blocks/CU (was 2 at 56K)
// Swapped-operand S^T = mfma(K, Q): P stays in registers; PV A-frags built
// with cvt_pk_bf16 + ds_bpermute (no P LDS round-trip, no fences).
// ---------------------------------------------------------------------------
__global__ __launch_bounds__(512, 6) void mha_fused(
    const void* __restrict__ Xv, const u16* __restrict__ WF,
    const void* __restrict__ wqv, const void* __restrict__ wkv,
    const void* __restrict__ wvv, const void* __restrict__ wrv,
    void* __restrict__ outv, const u32* __restrict__ flag, int useWF) {
  __shared__ __align__(16) u16 smem[24576];
  u16* Qf = smem;            // 8192 elems
  u16* Kf = smem + 8192;     // 8192
  u16* Vf = smem + 16384;    // 8192

  const bool isbf = (flag[0] != 0u);
  const int tid  = threadIdx.x;
  const int w    = tid >> 6;     // wave id: owns rows [16w, 16w+16)
  const int lane = tid & 63;
  const int quad = lane >> 4;
  const int col  = lane & 15;
  const int b    = blockIdx.x;

  // ---- stage X[b] through LDS (two halves) into per-wave A-frags ----
  s16x8 xfrag[8];
  {
    u32x4* xs = (u32x4*)smem;
#pragma unroll
    for (int half = 0; half < 2; ++half) {
      int cbase = half * 2048;
#pragma unroll
      for (int k = 0; k < 4; ++k) {
        int c  = cbase + tid + k * 512;       // 8-element chunk id
        int s  = c >> 5;                      // row 0..127
        int e0 = (c & 31) * 8;                // elem base within row
        U16x8 tmp;
        if (isbf) {
          const u32x4* xg = (const u32x4*)Xv + (size_t)b * 4096;
          u32x4 raw = xg[c];
          tmp = *(const U16x8*)&raw;
        } else {
          const f32x4* xg = (const f32x4*)Xv + (size_t)b * 8192;
          f32x4 lo = xg[2 * c], hi = xg[2 * c + 1];
#pragma unroll
          for (int j = 0; j < 4; ++j) { tmp.v[j] = f2bf(lo[j]); tmp.v[4 + j] = f2bf(hi[j]); }
        }
        xs[(((s >> 4) & 3) * 8 + (e0 >> 5)) * 64 + ((e0 >> 3) & 3) * 16 + (s & 15)] =
            *(const u32x4*)tmp.v;
      }
      __syncthreads();
      if ((w >> 2) == half) {
        int trl = w & 3;
#pragma unroll
        for (int ks = 0; ks < 8; ++ks) {
          u32x4 raw = xs[(trl * 8 + ks) * 64 + lane];
          xfrag[ks] = *(const s16x8*)&raw;
        }
      }
      __syncthreads();
    }
  }

  const u32x4* wf4 = ((const u32x4*)WF) + lane;

  for (int h = 0; h < H_; ++h) {
    // ---- projections: Q, K, V to LDS (R deferred to after PV) ----
    f32x4 acc[4];
    if (useWF) proj4_wf(wf4, 0 * 8 + h, xfrag, acc);
    else       proj4_direct(wqv, isbf, h, lane, xfrag, acc);
    scatter_qk(Qf, w, quad, col, acc);
    if (useWF) proj4_wf(wf4, 1 * 8 + h, xfrag, acc);
    else       proj4_direct(wkv, isbf, h, lane, xfrag, acc);
    scatter_qk(Kf, w, quad, col, acc);
    if (useWF) proj4_wf(wf4, 2 * 8 + h, xfrag, acc);
    else       proj4_direct(wvv, isbf, h, lane, xfrag, acc);
    scatter_v(Vf, w, quad, col, acc);
    __syncthreads();

    // ---- S^T = K Q^T : same LDS frags as before, operands SWAPPED.
    // C-frag: col (lane&15) = q within this wave's 16 rows,
    //         row = tS*16 + quad*4 + r = k index. Lane holds 32 of 128 k. ----
    s16x8 aq[2];
#pragma unroll
    for (int k2 = 0; k2 < 2; ++k2)
      aq[k2] = *(const s16x8*)(Qf + ((w * 2 + k2) * 64 + lane) * 8);
    f32x4 sacc[8];
#pragma unroll
    for (int tS = 0; tS < 8; ++tS) {
      sacc[tS] = (f32x4){0.f, 0.f, 0.f, 0.f};
#pragma unroll
      for (int k2 = 0; k2 < 2; ++k2) {
        s16x8 bk = *(const s16x8*)(Kf + ((tS * 2 + k2) * 64 + lane) * 8);
        sacc[tS] = __builtin_amdgcn_mfma_f32_16x16x32_bf16(bk, aq[k2], sacc[tS], 0, 0, 0);
      }
    }

    // ---- softmax: per-lane reduce over 32 k-values + 2 cross-quad shuffles ----
    float m = sacc[0][0];
#pragma unroll
    for (int tS = 0; tS < 8; ++tS)
#pragma unroll
      for (int r = 0; r < 4; ++r) m = fmaxf(m, sacc[tS][r]);
    m = fmaxf(m, __shfl_xor(m, 16));
    m = fmaxf(m, __shfl_xor(m, 32));
    float lsum = 0.f;
#pragma unroll
    for (int tS = 0; tS < 8; ++tS)
#pragma unroll
      for (int r = 0; r < 4; ++r) {
        float e = __expf(sacc[tS][r] - m);
        sacc[tS][r] = e;
        lsum += e;
      }
    lsum += __shfl_xor(lsum, 16);
    lsum += __shfl_xor(lsum, 32);
    float linv = 1.0f / lsum;

    // ---- pack P^T to bf16 pairs: wp[tS][c] = pk(P[k=tS*16+quad*4+2c],[+2c+1]) ----
    u32 wp[8][2];
#pragma unroll
    for (int tS = 0; tS < 8; ++tS) {
      wp[tS][0] = cvtpk_bf16(sacc[tS][0], sacc[tS][1]);
      wp[tS][1] = cvtpk_bf16(sacc[tS][2], sacc[tS][3]);
    }

    // ---- O = P V with in-register P: build A-frags via bpermute.
    // Lane (hi=quad, q=col) needs k = kt*32 + hi*8 + j; word m of the A-frag
    // comes from tile tS = 2kt + (hi>>1), source quad (hi&1)*2 + (m>>1). ----
    const int sl0 = (lane & 15) | ((lane & 16) << 1);   // q + ((quad&1)?32:0)
    const bool hiq = (lane >= 32);                      // quad>>1
    f32x4 oacc[4];
#pragma unroll
    for (int tc = 0; tc < 4; ++tc) oacc[tc] = (f32x4){0.f, 0.f, 0.f, 0.f};
#pragma unroll
    for (int kt = 0; kt < 4; ++kt) {
      int a00 = __shfl((int)wp[2 * kt][0],     sl0);
      int a01 = __shfl((int)wp[2 * kt][1],     sl0);
      int a10 = __shfl((int)wp[2 * kt + 1][0], sl0);
      int a11 = __shfl((int)wp[2 * kt + 1][1], sl0);
      int b00 = __shfl((int)wp[2 * kt][0],     sl0 + 16);
      int b01 = __shfl((int)wp[2 * kt][1],     sl0 + 16);
      int b10 = __shfl((int)wp[2 * kt + 1][0], sl0 + 16);
      int b11 = __shfl((int)wp[2 * kt + 1][1], sl0 + 16);
      u32x4 av;
      av[0] = (u32)(hiq ? a10 : a00);
      av[1] = (u32)(hiq ? a11 : a01);
      av[2] = (u32)(hiq ? b10 : b00);
      av[3] = (u32)(hiq ? b11 : b01);
      s16x8 ap = *(const s16x8*)&av;
#pragma unroll
      for (int tc = 0; tc < 4; ++tc) {
        s16x8 bv = *(const s16x8*)(Vf + ((kt * 4 + tc) * 64 + lane) * 8);
        oacc[tc] = __builtin_amdgcn_mfma_f32_16x16x32_bf16(ap, bv, oacc[tc], 0, 0, 0);
      }
    }

    // ---- residual projection (deferred: shortens ra liveness) ----
    f32x4 ra[4];
    if (useWF) proj4_wf(wf4, 3 * 8 + h, xfrag, ra);
    else       proj4_direct(wrv, isbf, h, lane, xfrag, ra);

    // 1/l for epilogue rows: O C-frag row = quad*4+r; sums live at lane&15==q
    float linv_e[4];
#pragma unroll
    for (int r = 0; r < 4; ++r) linv_e[r] = __shfl(linv, quad * 4 + r);

    // ---- epilogue: 1/l scaling + residual + ReLU, dtype-matched store ----
#pragma unroll
    for (int tc = 0; tc < 4; ++tc)
#pragma unroll
      for (int r = 0; r < 4; ++r) {
        float v = oacc[tc][r] * linv_e[r] + ra[tc][r];
        v = fmaxf(v, 0.f);
        int s = w * 16 + quad * 4 + r;
        size_t idx = ((size_t)b * S_ + s) * HD_ + h * D_ + tc * 16 + col;
        if (isbf) ((u16*)outv)[idx] = f2bf(v);
        else      ((float*)outv)[idx] = v;
      }
    __syncthreads();   // protect Qf/Kf/Vf before next head overwrites
  }
}

extern "C" void kernel_launch(void* const* d_in, const int* in_sizes, int n_in,
                              void* d_out, int out_size, void* d_ws, size_t ws_size,
                              hipStream_t stream) {
  const void* X  = d_in[0];
  const void* wq = d_in[1];
  const void* wk = d_in[2];
  const void* wv = d_in[3];
  const void* wr = d_in[4];

  u32* flag = (u32*)d_ws;                       // 4 B flag at ws offset 0
  u16* wf   = (u16*)((char*)d_ws + 4096);       // 1 MiB fragment cache
  int useWF = (ws_size >= (size_t)(1u << 20) + 4096) ? 1 : 0;

  probe_dtype<<<dim3(1), dim3(256), 0, stream>>>((const u32*)X, flag);
  if (useWF)
    repack_w<<<dim3(256), dim3(256), 0, stream>>>(wq, wk, wv, wr, flag, wf);
  mha_fused<<<dim3(B_), dim3(512), 0, stream>>>(X, wf, wq, wk, wv, wr, d_out, flag, useWF);
}

// Round 2
// 1020.980 us; speedup vs baseline: 1.1760x; 1.0265x over previous
//
#include <hip/hip_runtime.h>

#define B_ 1024
#define S_ 128
#define E_ 256
#define H_ 8
#define D_ 64
#define HD_ 512

typedef short s16x8 __attribute__((ext_vector_type(8)));   // 8 bf16 (guide §3)
typedef float f32x4 __attribute__((ext_vector_type(4)));
typedef unsigned int u32x4 __attribute__((ext_vector_type(4)));
typedef unsigned short u16;
typedef unsigned int u32;

struct U16x8 { u16 v[8]; };

__device__ __forceinline__ u16 f2bf(float f) {
  u32 u = __float_as_uint(f);
  u += 0x7FFFu + ((u >> 16) & 1u);   // round-to-nearest-even
  return (u16)(u >> 16);
}

// pack two f32 -> one u32 of 2x bf16 (lo = s0, hi = s1); no builtin on gfx950
__device__ __forceinline__ u32 cvtpk_bf16(float lo, float hi) {
  u32 r;
  asm("v_cvt_pk_bf16_f32 %0, %1, %2" : "=v"(r) : "v"(lo), "v"(hi));
  return r;
}

// ---------------------------------------------------------------------------
// Dtype probe: decide whether inputs are packed bf16 or float32.
// flag[0] = 1 (bf16) or 0 (f32), recomputed every launch (graph-safe).
// ---------------------------------------------------------------------------
__global__ __launch_bounds__(256) void probe_dtype(const u32* __restrict__ x,
                                                   u32* __restrict__ flag) {
  __shared__ int cnt;
  if (threadIdx.x == 0) cnt = 0;
  __syncthreads();
  u32 w = x[threadIdx.x];
  u32 e = (w >> 7) & 0xFFu;
  if (e > 96u && e < 160u) atomicAdd(&cnt, 1);
  __syncthreads();
  if (threadIdx.x == 0) flag[0] = (cnt > 128) ? 1u : 0u;
}

// ---------------------------------------------------------------------------
// Repack the four (E x HD) weights into bf16 MFMA B-fragment order:
// WF[(((w*8+h)*8+ks)*4+tc)*64+lane][j] = W_w[ks*32+(lane>>4)*8+j][h*64+tc*16+(lane&15)]
// ---------------------------------------------------------------------------
__global__ __launch_bounds__(256) void repack_w(
    const void* __restrict__ wqv, const void* __restrict__ wkv,
    const void* __restrict__ wvv, const void* __restrict__ wrv,
    const u32* __restrict__ flag, u16* __restrict__ wf) {
  bool isbf = (flag[0] != 0u);
  int t = blockIdx.x * 256 + threadIdx.x;   // 65536 threads total
  int lane = t & 63;
  int tc   = (t >> 6) & 3;
  int ks   = (t >> 8) & 7;
  int h    = (t >> 11) & 7;
  int w    = (t >> 14) & 3;
  const void* srcv = (w == 0) ? wqv : (w == 1) ? wkv : (w == 2) ? wvv : wrv;
  int n  = h * D_ + tc * 16 + (lane & 15);
  int e0 = ks * 32 + (lane >> 4) * 8;
  U16x8 tmp;
  if (isbf) {
    const u16* s = (const u16*)srcv;
#pragma unroll
    for (int j = 0; j < 8; ++j) tmp.v[j] = s[(e0 + j) * HD_ + n];
  } else {
    const float* s = (const float*)srcv;
#pragma unroll
    for (int j = 0; j < 8; ++j) tmp.v[j] = f2bf(s[(e0 + j) * HD_ + n]);
  }
  *(u32x4*)(wf + (size_t)t * 8) = *(const u32x4*)tmp.v;
}

// Projection via repacked fragments: one dwordx4 per B-frag.
__device__ __forceinline__ void proj4_wf(const u32x4* __restrict__ wf4lane, int base8,
                                         const s16x8 xfrag[8], f32x4 acc[4]) {
#pragma unroll
  for (int tc = 0; tc < 4; ++tc) acc[tc] = (f32x4){0.f, 0.f, 0.f, 0.f};
#pragma unroll
  for (int ks = 0; ks < 8; ++ks) {
#pragma unroll
    for (int tc = 0; tc < 4; ++tc) {
      u32x4 raw = wf4lane[((base8 * 8 + ks) * 4 + tc) * 64];
      s16x8 bfr = *(const s16x8*)&raw;
      acc[tc] = __builtin_amdgcn_mfma_f32_16x16x32_bf16(xfrag[ks], bfr, acc[tc], 0, 0, 0);
    }
  }
}

// Fallback (ws too small for WF): gather B-frags from the original layout.
__device__ __forceinline__ void proj4_direct(const void* __restrict__ srcv, bool isbf,
                                             int h, int lane, const s16x8 xfrag[8],
                                             f32x4 acc[4]) {
#pragma unroll
  for (int tc = 0; tc < 4; ++tc) acc[tc] = (f32x4){0.f, 0.f, 0.f, 0.f};
  int e8 = (lane >> 4) * 8;
  int nc = h * D_ + (lane & 15);
#pragma unroll
  for (int ks = 0; ks < 8; ++ks) {
#pragma unroll
    for (int tc = 0; tc < 4; ++tc) {
      U16x8 tmp;
      if (isbf) {
        const u16* s = (const u16*)srcv;
#pragma unroll
        for (int j = 0; j < 8; ++j) tmp.v[j] = s[(ks * 32 + e8 + j) * HD_ + nc + tc * 16];
      } else {
        const float* s = (const float*)srcv;
#pragma unroll
        for (int j = 0; j < 8; ++j) tmp.v[j] = f2bf(s[(ks * 32 + e8 + j) * HD_ + nc + tc * 16]);
      }
      s16x8 bfr = *(const s16x8*)tmp.v;
      acc[tc] = __builtin_amdgcn_mfma_f32_16x16x32_bf16(xfrag[ks], bfr, acc[tc], 0, 0, 0);
    }
  }
}

// Scatter projection C-frags (row=quad*4+r, col=tc*16+col) into A/B-frag-major
// LDS layout — same index formula for Q and K.
__device__ __forceinline__ void scatter_qk(u16* dst, int w, int quad, int col,
                                           const f32x4 acc[4]) {
#pragma unroll
  for (int tc = 0; tc < 4; ++tc) {
    int ks2 = tc >> 1;
    int q2  = (tc & 1) * 2 + (col >> 3);
#pragma unroll
    for (int r = 0; r < 4; ++r)
      dst[(((w * 2 + ks2) * 64) + q2 * 16 + quad * 4 + r) * 8 + (col & 7)] =
          f2bf(acc[tc][r]);
  }
}

// V goes to B-frag-major for O = P@V (k = s', n = d).
__device__ __forceinline__ void scatter_v(u16* Vf, int w, int quad, int col,
                                          const f32x4 acc[4]) {
#pragma unroll
  for (int tc = 0; tc < 4; ++tc)
#pragma unroll
    for (int r = 0; r < 4; ++r) {
      int srow = quad * 4 + r;
      int q2   = (w & 1) * 2 + (srow >> 3);
      Vf[((((w >> 1) * 4 + tc) * 64) + q2 * 16 + col) * 8 + (srow & 7)] =
          f2bf(acc[tc][r]);
    }
}

// ---------------------------------------------------------------------------
// Fused MHA: one workgroup per batch, 8 waves, head loop inside.
// LDS (48 KiB): Qf 16K | Kf 16K | Vf 16K
// Swapped-operand S^T = mfma(K, Q): P stays in registers; PV A-frags built
// with cvt_pk_bf16 + shfl (no P LDS round-trip, no fences).
// NOTE: no min-waves hint — (512,6) forced VGPR=40 + ~480 MB/dispatch of
// scratch spill traffic (FETCH 397 MB, WRITE 427 MB). Let the allocator
// land naturally (~84 VGPR in round 0) and take whatever occupancy follows.
// ---------------------------------------------------------------------------
__global__ __launch_bounds__(512) void mha_fused(
    const void* __restrict__ Xv, const u16* __restrict__ WF,
    const void* __restrict__ wqv, const void* __restrict__ wkv,
    const void* __restrict__ wvv, const void* __restrict__ wrv,
    void* __restrict__ outv, const u32* __restrict__ flag, int useWF) {
  __shared__ __align__(16) u16 smem[24576];
  u16* Qf = smem;            // 8192 elems
  u16* Kf = smem + 8192;     // 8192
  u16* Vf = smem + 16384;    // 8192

  const bool isbf = (flag[0] != 0u);
  const int tid  = threadIdx.x;
  const int w    = tid >> 6;     // wave id: owns rows [16w, 16w+16)
  const int lane = tid & 63;
  const int quad = lane >> 4;
  const int col  = lane & 15;
  const int b    = blockIdx.x;

  // ---- stage X[b] through LDS (two halves) into per-wave A-frags ----
  s16x8 xfrag[8];
  {
    u32x4* xs = (u32x4*)smem;
#pragma unroll
    for (int half = 0; half < 2; ++half) {
      int cbase = half * 2048;
#pragma unroll
      for (int k = 0; k < 4; ++k) {
        int c  = cbase + tid + k * 512;       // 8-element chunk id
        int s  = c >> 5;                      // row 0..127
        int e0 = (c & 31) * 8;                // elem base within row
        U16x8 tmp;
        if (isbf) {
          const u32x4* xg = (const u32x4*)Xv + (size_t)b * 4096;
          u32x4 raw = xg[c];
          tmp = *(const U16x8*)&raw;
        } else {
          const f32x4* xg = (const f32x4*)Xv + (size_t)b * 8192;
          f32x4 lo = xg[2 * c], hi = xg[2 * c + 1];
#pragma unroll
          for (int j = 0; j < 4; ++j) { tmp.v[j] = f2bf(lo[j]); tmp.v[4 + j] = f2bf(hi[j]); }
        }
        xs[(((s >> 4) & 3) * 8 + (e0 >> 5)) * 64 + ((e0 >> 3) & 3) * 16 + (s & 15)] =
            *(const u32x4*)tmp.v;
      }
      __syncthreads();
      if ((w >> 2) == half) {
        int trl = w & 3;
#pragma unroll
        for (int ks = 0; ks < 8; ++ks) {
          u32x4 raw = xs[(trl * 8 + ks) * 64 + lane];
          xfrag[ks] = *(const s16x8*)&raw;
        }
      }
      __syncthreads();
    }
  }

  const u32x4* wf4 = ((const u32x4*)WF) + lane;

  for (int h = 0; h < H_; ++h) {
    // ---- projections: Q, K, V to LDS (R deferred to after PV) ----
    f32x4 acc[4];
    if (useWF) proj4_wf(wf4, 0 * 8 + h, xfrag, acc);
    else       proj4_direct(wqv, isbf, h, lane, xfrag, acc);
    scatter_qk(Qf, w, quad, col, acc);
    if (useWF) proj4_wf(wf4, 1 * 8 + h, xfrag, acc);
    else       proj4_direct(wkv, isbf, h, lane, xfrag, acc);
    scatter_qk(Kf, w, quad, col, acc);
    if (useWF) proj4_wf(wf4, 2 * 8 + h, xfrag, acc);
    else       proj4_direct(wvv, isbf, h, lane, xfrag, acc);
    scatter_v(Vf, w, quad, col, acc);
    __syncthreads();

    // ---- S^T = K Q^T : same LDS frags as before, operands SWAPPED.
    // C-frag: col (lane&15) = q within this wave's 16 rows,
    //         row = tS*16 + quad*4 + r = k index. Lane holds 32 of 128 k. ----
    s16x8 aq[2];
#pragma unroll
    for (int k2 = 0; k2 < 2; ++k2)
      aq[k2] = *(const s16x8*)(Qf + ((w * 2 + k2) * 64 + lane) * 8);
    f32x4 sacc[8];
#pragma unroll
    for (int tS = 0; tS < 8; ++tS) {
      sacc[tS] = (f32x4){0.f, 0.f, 0.f, 0.f};
#pragma unroll
      for (int k2 = 0; k2 < 2; ++k2) {
        s16x8 bk = *(const s16x8*)(Kf + ((tS * 2 + k2) * 64 + lane) * 8);
        sacc[tS] = __builtin_amdgcn_mfma_f32_16x16x32_bf16(bk, aq[k2], sacc[tS], 0, 0, 0);
      }
    }

    // ---- softmax: per-lane reduce over 32 k-values + 2 cross-quad shuffles ----
    float m = sacc[0][0];
#pragma unroll
    for (int tS = 0; tS < 8; ++tS)
#pragma unroll
      for (int r = 0; r < 4; ++r) m = fmaxf(m, sacc[tS][r]);
    m = fmaxf(m, __shfl_xor(m, 16));
    m = fmaxf(m, __shfl_xor(m, 32));
    float lsum = 0.f;
#pragma unroll
    for (int tS = 0; tS < 8; ++tS)
#pragma unroll
      for (int r = 0; r < 4; ++r) {
        float e = __expf(sacc[tS][r] - m);
        sacc[tS][r] = e;
        lsum += e;
      }
    lsum += __shfl_xor(lsum, 16);
    lsum += __shfl_xor(lsum, 32);
    float linv = 1.0f / lsum;

    // ---- pack P^T to bf16 pairs: wp[tS][c] = pk(P[k=tS*16+quad*4+2c],[+2c+1]) ----
    u32 wp[8][2];
#pragma unroll
    for (int tS = 0; tS < 8; ++tS) {
      wp[tS][0] = cvtpk_bf16(sacc[tS][0], sacc[tS][1]);
      wp[tS][1] = cvtpk_bf16(sacc[tS][2], sacc[tS][3]);
    }

    // ---- O = P V with in-register P: build A-frags via shfl.
    // Lane (hi=quad, q=col) needs k = kt*32 + hi*8 + j; word m of the A-frag
    // comes from tile tS = 2kt + (hi>>1), source quad (hi&1)*2 + (m>>1). ----
    const int sl0 = (lane & 15) | ((lane & 16) << 1);   // q + ((quad&1)?32:0)
    const bool hiq = (lane >= 32);                      // quad>>1
    f32x4 oacc[4];
#pragma unroll
    for (int tc = 0; tc < 4; ++tc) oacc[tc] = (f32x4){0.f, 0.f, 0.f, 0.f};
#pragma unroll
    for (int kt = 0; kt < 4; ++kt) {
      int a00 = __shfl((int)wp[2 * kt][0],     sl0);
      int a01 = __shfl((int)wp[2 * kt][1],     sl0);
      int a10 = __shfl((int)wp[2 * kt + 1][0], sl0);
      int a11 = __shfl((int)wp[2 * kt + 1][1], sl0);
      int b00 = __shfl((int)wp[2 * kt][0],     sl0 + 16);
      int b01 = __shfl((int)wp[2 * kt][1],     sl0 + 16);
      int b10 = __shfl((int)wp[2 * kt + 1][0], sl0 + 16);
      int b11 = __shfl((int)wp[2 * kt + 1][1], sl0 + 16);
      u32x4 av;
      av[0] = (u32)(hiq ? a10 : a00);
      av[1] = (u32)(hiq ? a11 : a01);
      av[2] = (u32)(hiq ? b10 : b00);
      av[3] = (u32)(hiq ? b11 : b01);
      s16x8 ap = *(const s16x8*)&av;
#pragma unroll
      for (int tc = 0; tc < 4; ++tc) {
        s16x8 bv = *(const s16x8*)(Vf + ((kt * 4 + tc) * 64 + lane) * 8);
        oacc[tc] = __builtin_amdgcn_mfma_f32_16x16x32_bf16(ap, bv, oacc[tc], 0, 0, 0);
      }
    }

    // ---- residual projection (deferred: shortens ra liveness) ----
    f32x4 ra[4];
    if (useWF) proj4_wf(wf4, 3 * 8 + h, xfrag, ra);
    else       proj4_direct(wrv, isbf, h, lane, xfrag, ra);

    // 1/l for epilogue rows: O C-frag row = quad*4+r; sums live at lane&15==q
    float linv_e[4];
#pragma unroll
    for (int r = 0; r < 4; ++r) linv_e[r] = __shfl(linv, quad * 4 + r);

    // ---- epilogue: 1/l scaling + residual + ReLU, dtype-matched store ----
#pragma unroll
    for (int tc = 0; tc < 4; ++tc)
#pragma unroll
      for (int r = 0; r < 4; ++r) {
        float v = oacc[tc][r] * linv_e[r] + ra[tc][r];
        v = fmaxf(v, 0.f);
        int s = w * 16 + quad * 4 + r;
        size_t idx = ((size_t)b * S_ + s) * HD_ + h * D_ + tc * 16 + col;
        if (isbf) ((u16*)outv)[idx] = f2bf(v);
        else      ((float*)outv)[idx] = v;
      }
    __syncthreads();   // protect Qf/Kf/Vf before next head overwrites
  }
}

extern "C" void kernel_launch(void* const* d_in, const int* in_sizes, int n_in,
                              void* d_out, int out_size, void* d_ws, size_t ws_size,
                              hipStream_t stream) {
  const void* X  = d_in[0];
  const void* wq = d_in[1];
  const void* wk = d_in[2];
  const void* wv = d_in[3];
  const void* wr = d_in[4];

  u32* flag = (u32*)d_ws;                       // 4 B flag at ws offset 0
  u16* wf   = (u16*)((char*)d_ws + 4096);       // 1 MiB fragment cache
  int useWF = (ws_size >= (size_t)(1u << 20) + 4096) ? 1 : 0;

  probe_dtype<<<dim3(1), dim3(256), 0, stream>>>((const u32*)X, flag);
  if (useWF)
    repack_w<<<dim3(256), dim3(256), 0, stream>>>(wq, wk, wv, wr, flag, wf);
  mha_fused<<<dim3(B_), dim3(512), 0, stream>>>(X, wf, wq, wk, wv, wr, d_out, flag, useWF);
}

// Round 3
// 755.020 us; speedup vs baseline: 1.5903x; 1.3523x over previous
//
#include <hip/hip_runtime.h>

#define B_ 1024
#define S_ 128
#define E_ 256
#define H_ 8
#define D_ 64
#define HD_ 512

typedef short s16x8 __attribute__((ext_vector_type(8)));   // 8 bf16 (guide §3)
typedef float f32x4 __attribute__((ext_vector_type(4)));
typedef unsigned int u32x4 __attribute__((ext_vector_type(4)));
typedef unsigned short u16;
typedef unsigned int u32;

struct U16x8 { u16 v[8]; };

__device__ __forceinline__ u16 f2bf(float f) {
  u32 u = __float_as_uint(f);
  u += 0x7FFFu + ((u >> 16) & 1u);   // round-to-nearest-even
  return (u16)(u >> 16);
}

// pack two f32 -> one u32 of 2x bf16 (lo = s0, hi = s1); no builtin on gfx950
__device__ __forceinline__ u32 cvtpk_bf16(float lo, float hi) {
  u32 r;
  asm("v_cvt_pk_bf16_f32 %0, %1, %2" : "=v"(r) : "v"(lo), "v"(hi));
  return r;
}

// ---------------------------------------------------------------------------
// Dtype probe: decide whether inputs are packed bf16 or float32.
// flag[0] = 1 (bf16) or 0 (f32), recomputed every launch (graph-safe).
// ---------------------------------------------------------------------------
__global__ __launch_bounds__(256) void probe_dtype(const u32* __restrict__ x,
                                                   u32* __restrict__ flag) {
  __shared__ int cnt;
  if (threadIdx.x == 0) cnt = 0;
  __syncthreads();
  u32 w = x[threadIdx.x];
  u32 e = (w >> 7) & 0xFFu;
  if (e > 96u && e < 160u) atomicAdd(&cnt, 1);
  __syncthreads();
  if (threadIdx.x == 0) flag[0] = (cnt > 128) ? 1u : 0u;
}

// ---------------------------------------------------------------------------
// Repack the four (E x HD) weights into bf16 MFMA B-fragment order:
// WF[(((w*8+h)*8+ks)*4+tc)*64+lane][j] = W_w[ks*32+(lane>>4)*8+j][h*64+tc*16+(lane&15)]
// ---------------------------------------------------------------------------
__global__ __launch_bounds__(256) void repack_w(
    const void* __restrict__ wqv, const void* __restrict__ wkv,
    const void* __restrict__ wvv, const void* __restrict__ wrv,
    const u32* __restrict__ flag, u16* __restrict__ wf) {
  bool isbf = (flag[0] != 0u);
  int t = blockIdx.x * 256 + threadIdx.x;   // 65536 threads total
  int lane = t & 63;
  int tc   = (t >> 6) & 3;
  int ks   = (t >> 8) & 7;
  int h    = (t >> 11) & 7;
  int w    = (t >> 14) & 3;
  const void* srcv = (w == 0) ? wqv : (w == 1) ? wkv : (w == 2) ? wvv : wrv;
  int n  = h * D_ + tc * 16 + (lane & 15);
  int e0 = ks * 32 + (lane >> 4) * 8;
  U16x8 tmp;
  if (isbf) {
    const u16* s = (const u16*)srcv;
#pragma unroll
    for (int j = 0; j < 8; ++j) tmp.v[j] = s[(e0 + j) * HD_ + n];
  } else {
    const float* s = (const float*)srcv;
#pragma unroll
    for (int j = 0; j < 8; ++j) tmp.v[j] = f2bf(s[(e0 + j) * HD_ + n]);
  }
  *(u32x4*)(wf + (size_t)t * 8) = *(const u32x4*)tmp.v;
}

// Projection via repacked fragments: one dwordx4 per B-frag.
__device__ __forceinline__ void proj4_wf(const u32x4* __restrict__ wf4lane, int base8,
                                         const s16x8 xfrag[8], f32x4 acc[4]) {
#pragma unroll
  for (int tc = 0; tc < 4; ++tc) acc[tc] = (f32x4){0.f, 0.f, 0.f, 0.f};
#pragma unroll
  for (int ks = 0; ks < 8; ++ks) {
#pragma unroll
    for (int tc = 0; tc < 4; ++tc) {
      u32x4 raw = wf4lane[((base8 * 8 + ks) * 4 + tc) * 64];
      s16x8 bfr = *(const s16x8*)&raw;
      acc[tc] = __builtin_amdgcn_mfma_f32_16x16x32_bf16(xfrag[ks], bfr, acc[tc], 0, 0, 0);
    }
  }
}

// Fallback (ws too small for WF): gather B-frags from the original layout.
__device__ __forceinline__ void proj4_direct(const void* __restrict__ srcv, bool isbf,
                                             int h, int lane, const s16x8 xfrag[8],
                                             f32x4 acc[4]) {
#pragma unroll
  for (int tc = 0; tc < 4; ++tc) acc[tc] = (f32x4){0.f, 0.f, 0.f, 0.f};
  int e8 = (lane >> 4) * 8;
  int nc = h * D_ + (lane & 15);
#pragma unroll
  for (int ks = 0; ks < 8; ++ks) {
#pragma unroll
    for (int tc = 0; tc < 4; ++tc) {
      U16x8 tmp;
      if (isbf) {
        const u16* s = (const u16*)srcv;
#pragma unroll
        for (int j = 0; j < 8; ++j) tmp.v[j] = s[(ks * 32 + e8 + j) * HD_ + nc + tc * 16];
      } else {
        const float* s = (const float*)srcv;
#pragma unroll
        for (int j = 0; j < 8; ++j) tmp.v[j] = f2bf(s[(ks * 32 + e8 + j) * HD_ + nc + tc * 16]);
      }
      s16x8 bfr = *(const s16x8*)tmp.v;
      acc[tc] = __builtin_amdgcn_mfma_f32_16x16x32_bf16(xfrag[ks], bfr, acc[tc], 0, 0, 0);
    }
  }
}

// Scatter projection C-frags (row=quad*4+r, col=tc*16+col) into A/B-frag-major
// LDS layout — same index formula for Q and K.
__device__ __forceinline__ void scatter_qk(u16* dst, int w, int quad, int col,
                                           const f32x4 acc[4]) {
#pragma unroll
  for (int tc = 0; tc < 4; ++tc) {
    int ks2 = tc >> 1;
    int q2  = (tc & 1) * 2 + (col >> 3);
#pragma unroll
    for (int r = 0; r < 4; ++r)
      dst[(((w * 2 + ks2) * 64) + q2 * 16 + quad * 4 + r) * 8 + (col & 7)] =
          f2bf(acc[tc][r]);
  }
}

// V goes to B-frag-major for O = P@V (k = s', n = d).
__device__ __forceinline__ void scatter_v(u16* Vf, int w, int quad, int col,
                                          const f32x4 acc[4]) {
#pragma unroll
  for (int tc = 0; tc < 4; ++tc)
#pragma unroll
    for (int r = 0; r < 4; ++r) {
      int srow = quad * 4 + r;
      int q2   = (w & 1) * 2 + (srow >> 3);
      Vf[((((w >> 1) * 4 + tc) * 64) + q2 * 16 + col) * 8 + (srow & 7)] =
          f2bf(acc[tc][r]);
    }
}

// ---------------------------------------------------------------------------
// Fused MHA, head-pipelined: one workgroup per batch, 8 waves.
// Region h (one barrier each): project head h (into K/V buf h&1) WHILE
// attending head h-1 (from K/V buf (h-1)&1). The two streams are independent,
// so proj's L2/L3 weight-load latency hides under attn compute and attn's
// DS-shuffle latency hides under proj MFMAs.
// LDS (80 KiB): Qf 16K (per-wave, single) | Kf x2 32K | Vf x2 32K -> 2 blk/CU.
// Q needs no double buffer: wave w reads only its own scatter, so the two
// QK^T A-frags are read back immediately (intra-wave lgkmcnt) and carried in
// registers across the region boundary.
// ---------------------------------------------------------------------------
__global__ __launch_bounds__(512, 2) void mha_fused(
    const void* __restrict__ Xv, const u16* __restrict__ WF,
    const void* __restrict__ wqv, const void* __restrict__ wkv,
    const void* __restrict__ wvv, const void* __restrict__ wrv,
    void* __restrict__ outv, const u32* __restrict__ flag, int useWF) {
  __shared__ __align__(16) u16 smem[40960];   // 80 KiB
  u16* Qf = smem;                              // 8192 elems

  const bool isbf = (flag[0] != 0u);
  const int tid  = threadIdx.x;
  const int w    = tid >> 6;     // wave id: owns rows [16w, 16w+16)
  const int lane = tid & 63;
  const int quad = lane >> 4;
  const int col  = lane & 15;
  const int b    = blockIdx.x;

  // ---- stage X[b] through LDS (two halves) into per-wave A-frags ----
  s16x8 xfrag[8];
  {
    u32x4* xs = (u32x4*)smem;
#pragma unroll
    for (int half = 0; half < 2; ++half) {
      int cbase = half * 2048;
#pragma unroll
      for (int k = 0; k < 4; ++k) {
        int c  = cbase + tid + k * 512;       // 8-element chunk id
        int s  = c >> 5;                      // row 0..127
        int e0 = (c & 31) * 8;                // elem base within row
        U16x8 tmp;
        if (isbf) {
          const u32x4* xg = (const u32x4*)Xv + (size_t)b * 4096;
          u32x4 raw = xg[c];
          tmp = *(const U16x8*)&raw;
        } else {
          const f32x4* xg = (const f32x4*)Xv + (size_t)b * 8192;
          f32x4 lo = xg[2 * c], hi = xg[2 * c + 1];
#pragma unroll
          for (int j = 0; j < 4; ++j) { tmp.v[j] = f2bf(lo[j]); tmp.v[4 + j] = f2bf(hi[j]); }
        }
        xs[(((s >> 4) & 3) * 8 + (e0 >> 5)) * 64 + ((e0 >> 3) & 3) * 16 + (s & 15)] =
            *(const u32x4*)tmp.v;
      }
      __syncthreads();
      if ((w >> 2) == half) {
        int trl = w & 3;
#pragma unroll
        for (int ks = 0; ks < 8; ++ks) {
          u32x4 raw = xs[(trl * 8 + ks) * 64 + lane];
          xfrag[ks] = *(const s16x8*)&raw;
        }
      }
      __syncthreads();
    }
  }

  const u32x4* wf4 = ((const u32x4*)WF) + lane;

  s16x8 aq[2];   // QK^T A-frags for the head currently in flight (register-carried)

  // ---- prologue: project Q,K,V for head 0 into buffer 0 ----
  {
    f32x4 acc[4];
    if (useWF) proj4_wf(wf4, 0 * 8 + 0, xfrag, acc);
    else       proj4_direct(wqv, isbf, 0, lane, xfrag, acc);
    scatter_qk(Qf, w, quad, col, acc);
    if (useWF) proj4_wf(wf4, 1 * 8 + 0, xfrag, acc);
    else       proj4_direct(wkv, isbf, 0, lane, xfrag, acc);
    scatter_qk(smem + 8192, w, quad, col, acc);
    if (useWF) proj4_wf(wf4, 2 * 8 + 0, xfrag, acc);
    else       proj4_direct(wvv, isbf, 0, lane, xfrag, acc);
    scatter_v(smem + 24576, w, quad, col, acc);
    aq[0] = *(const s16x8*)(Qf + ((w * 2 + 0) * 64 + lane) * 8);
    aq[1] = *(const s16x8*)(Qf + ((w * 2 + 1) * 64 + lane) * 8);
  }
  __syncthreads();

  for (int h = 1; h <= H_; ++h) {
    const int hp = h - 1;
    u16* Kp = smem + 8192  + (hp & 1) * 8192;
    u16* Vp = smem + 24576 + (hp & 1) * 8192;

    // ---- pipelined stream A: project head h into buffer h&1 ----
    s16x8 aqn[2];
    if (h < H_) {
      u16* Kc = smem + 8192  + (h & 1) * 8192;
      u16* Vc = smem + 24576 + (h & 1) * 8192;
      f32x4 acc[4];
      if (useWF) proj4_wf(wf4, 0 * 8 + h, xfrag, acc);
      else       proj4_direct(wqv, isbf, h, lane, xfrag, acc);
      scatter_qk(Qf, w, quad, col, acc);
      if (useWF) proj4_wf(wf4, 1 * 8 + h, xfrag, acc);
      else       proj4_direct(wkv, isbf, h, lane, xfrag, acc);
      scatter_qk(Kc, w, quad, col, acc);
      if (useWF) proj4_wf(wf4, 2 * 8 + h, xfrag, acc);
      else       proj4_direct(wvv, isbf, h, lane, xfrag, acc);
      scatter_v(Vc, w, quad, col, acc);
      aqn[0] = *(const s16x8*)(Qf + ((w * 2 + 0) * 64 + lane) * 8);
      aqn[1] = *(const s16x8*)(Qf + ((w * 2 + 1) * 64 + lane) * 8);
    }

    // ---- pipelined stream B: attention for head hp from buffer hp&1 ----
    // S^T = K Q^T (swapped operands): lane holds P column-slice, 32 of 128 k.
    f32x4 sacc[8];
#pragma unroll
    for (int tS = 0; tS < 8; ++tS) {
      sacc[tS] = (f32x4){0.f, 0.f, 0.f, 0.f};
#pragma unroll
      for (int k2 = 0; k2 < 2; ++k2) {
        s16x8 bk = *(const s16x8*)(Kp + ((tS * 2 + k2) * 64 + lane) * 8);
        sacc[tS] = __builtin_amdgcn_mfma_f32_16x16x32_bf16(bk, aq[k2], sacc[tS], 0, 0, 0);
      }
    }

    // softmax: per-lane reduce over 32 k-values + 2 cross-quad shuffles
    float m = sacc[0][0];
#pragma unroll
    for (int tS = 0; tS < 8; ++tS)
#pragma unroll
      for (int r = 0; r < 4; ++r) m = fmaxf(m, sacc[tS][r]);
    m = fmaxf(m, __shfl_xor(m, 16));
    m = fmaxf(m, __shfl_xor(m, 32));
    float lsum = 0.f;
#pragma unroll
    for (int tS = 0; tS < 8; ++tS)
#pragma unroll
      for (int r = 0; r < 4; ++r) {
        float e = __expf(sacc[tS][r] - m);
        sacc[tS][r] = e;
        lsum += e;
      }
    lsum += __shfl_xor(lsum, 16);
    lsum += __shfl_xor(lsum, 32);
    float linv = 1.0f / lsum;

    // pack P^T to bf16 pairs
    u32 wp[8][2];
#pragma unroll
    for (int tS = 0; tS < 8; ++tS) {
      wp[tS][0] = cvtpk_bf16(sacc[tS][0], sacc[tS][1]);
      wp[tS][1] = cvtpk_bf16(sacc[tS][2], sacc[tS][3]);
    }

    // O = P V with in-register P: A-frags via shfl
    const int sl0 = (lane & 15) | ((lane & 16) << 1);   // q + ((quad&1)?32:0)
    const bool hiq = (lane >= 32);                      // quad>>1
    f32x4 oacc[4];
#pragma unroll
    for (int tc = 0; tc < 4; ++tc) oacc[tc] = (f32x4){0.f, 0.f, 0.f, 0.f};
#pragma unroll
    for (int kt = 0; kt < 4; ++kt) {
      int a00 = __shfl((int)wp[2 * kt][0],     sl0);
      int a01 = __shfl((int)wp[2 * kt][1],     sl0);
      int a10 = __shfl((int)wp[2 * kt + 1][0], sl0);
      int a11 = __shfl((int)wp[2 * kt + 1][1], sl0);
      int b00 = __shfl((int)wp[2 * kt][0],     sl0 + 16);
      int b01 = __shfl((int)wp[2 * kt][1],     sl0 + 16);
      int b10 = __shfl((int)wp[2 * kt + 1][0], sl0 + 16);
      int b11 = __shfl((int)wp[2 * kt + 1][1], sl0 + 16);
      u32x4 av;
      av[0] = (u32)(hiq ? a10 : a00);
      av[1] = (u32)(hiq ? a11 : a01);
      av[2] = (u32)(hiq ? b10 : b00);
      av[3] = (u32)(hiq ? b11 : b01);
      s16x8 ap = *(const s16x8*)&av;
#pragma unroll
      for (int tc = 0; tc < 4; ++tc) {
        s16x8 bv = *(const s16x8*)(Vp + ((kt * 4 + tc) * 64 + lane) * 8);
        oacc[tc] = __builtin_amdgcn_mfma_f32_16x16x32_bf16(ap, bv, oacc[tc], 0, 0, 0);
      }
    }

    // residual projection for head hp
    f32x4 ra[4];
    if (useWF) proj4_wf(wf4, 3 * 8 + hp, xfrag, ra);
    else       proj4_direct(wrv, isbf, hp, lane, xfrag, ra);

    // 1/l for epilogue rows
    float linv_e[4];
#pragma unroll
    for (int r = 0; r < 4; ++r) linv_e[r] = __shfl(linv, quad * 4 + r);

    // epilogue: 1/l scaling + residual + ReLU, dtype-matched store
#pragma unroll
    for (int tc = 0; tc < 4; ++tc)
#pragma unroll
      for (int r = 0; r < 4; ++r) {
        float v = oacc[tc][r] * linv_e[r] + ra[tc][r];
        v = fmaxf(v, 0.f);
        int s = w * 16 + quad * 4 + r;
        size_t idx = ((size_t)b * S_ + s) * HD_ + hp * D_ + tc * 16 + col;
        if (isbf) ((u16*)outv)[idx] = f2bf(v);
        else      ((float*)outv)[idx] = v;
      }

    if (h < H_) { aq[0] = aqn[0]; aq[1] = aqn[1]; }
    __syncthreads();   // buffer h&1 complete; buffer hp&1 free for reuse
  }
}

extern "C" void kernel_launch(void* const* d_in, const int* in_sizes, int n_in,
                              void* d_out, int out_size, void* d_ws, size_t ws_size,
                              hipStream_t stream) {
  const void* X  = d_in[0];
  const void* wq = d_in[1];
  const void* wk = d_in[2];
  const void* wv = d_in[3];
  const void* wr = d_in[4];

  u32* flag = (u32*)d_ws;                       // 4 B flag at ws offset 0
  u16* wf   = (u16*)((char*)d_ws + 4096);       // 1 MiB fragment cache
  int useWF = (ws_size >= (size_t)(1u << 20) + 4096) ? 1 : 0;

  probe_dtype<<<dim3(1), dim3(256), 0, stream>>>((const u32*)X, flag);
  if (useWF)
    repack_w<<<dim3(256), dim3(256), 0, stream>>>(wq, wk, wv, wr, flag, wf);
  mha_fused<<<dim3(B_), dim3(512), 0, stream>>>(X, wf, wq, wk, wv, wr, d_out, flag, useWF);
}

// Round 4
// 579.602 us; speedup vs baseline: 2.0716x; 1.3027x over previous
//
#include <hip/hip_runtime.h>

#define B_ 1024
#define S_ 128
#define E_ 256
#define H_ 8
#define D_ 64
#define HD_ 512

typedef short s16x8 __attribute__((ext_vector_type(8)));   // 8 bf16 (guide §3)
typedef float f32x4 __attribute__((ext_vector_type(4)));
typedef unsigned int u32x4 __attribute__((ext_vector_type(4)));
typedef unsigned short u16;
typedef unsigned int u32;

struct U16x8 { u16 v[8]; };

__device__ __forceinline__ u16 f2bf(float f) {
  u32 u = __float_as_uint(f);
  u += 0x7FFFu + ((u >> 16) & 1u);   // round-to-nearest-even
  return (u16)(u >> 16);
}

// pack two f32 -> one u32 of 2x bf16 (lo = s0, hi = s1); no builtin on gfx950
__device__ __forceinline__ u32 cvtpk_bf16(float lo, float hi) {
  u32 r;
  asm("v_cvt_pk_bf16_f32 %0, %1, %2" : "=v"(r) : "v"(lo), "v"(hi));
  return r;
}

// async DMA one 32 KiB weight slice (frag-linear) into LDS: 512 thr x 4 x 16B
__device__ __forceinline__ void dma_w(const u16* __restrict__ WF, int base8,
                                      u16* dst, int tid) {
  const char* g = (const char*)WF + (size_t)base8 * 32768 + (size_t)tid * 16;
  char* l = (char*)dst + tid * 16;
#pragma unroll
  for (int j = 0; j < 4; ++j)
    __builtin_amdgcn_global_load_lds(
        (const __attribute__((address_space(1))) void*)(g + j * 8192),
        (__attribute__((address_space(3))) void*)(l + j * 8192), 16, 0, 0);
}

// ---------------------------------------------------------------------------
// Dtype probe: decide whether inputs are packed bf16 or float32.
// flag[0] = 1 (bf16) or 0 (f32), recomputed every launch (graph-safe).
// ---------------------------------------------------------------------------
__global__ __launch_bounds__(256) void probe_dtype(const u32* __restrict__ x,
                                                   u32* __restrict__ flag) {
  __shared__ int cnt;
  if (threadIdx.x == 0) cnt = 0;
  __syncthreads();
  u32 w = x[threadIdx.x];
  u32 e = (w >> 7) & 0xFFu;
  if (e > 96u && e < 160u) atomicAdd(&cnt, 1);
  __syncthreads();
  if (threadIdx.x == 0) flag[0] = (cnt > 128) ? 1u : 0u;
}

// ---------------------------------------------------------------------------
// Repack the four (E x HD) weights into bf16 MFMA B-fragment order:
// WF[(((w*8+h)*8+ks)*4+tc)*64+lane][j] = W_w[ks*32+(lane>>4)*8+j][h*64+tc*16+(lane&15)]
// Each (w,h) slice is a contiguous 32 KiB block -> DMA-able with global_load_lds.
// ---------------------------------------------------------------------------
__global__ __launch_bounds__(256) void repack_w(
    const void* __restrict__ wqv, const void* __restrict__ wkv,
    const void* __restrict__ wvv, const void* __restrict__ wrv,
    const u32* __restrict__ flag, u16* __restrict__ wf) {
  bool isbf = (flag[0] != 0u);
  int t = blockIdx.x * 256 + threadIdx.x;   // 65536 threads total
  int lane = t & 63;
  int tc   = (t >> 6) & 3;
  int ks   = (t >> 8) & 7;
  int h    = (t >> 11) & 7;
  int w    = (t >> 14) & 3;
  const void* srcv = (w == 0) ? wqv : (w == 1) ? wkv : (w == 2) ? wvv : wrv;
  int n  = h * D_ + tc * 16 + (lane & 15);
  int e0 = ks * 32 + (lane >> 4) * 8;
  U16x8 tmp;
  if (isbf) {
    const u16* s = (const u16*)srcv;
#pragma unroll
    for (int j = 0; j < 8; ++j) tmp.v[j] = s[(e0 + j) * HD_ + n];
  } else {
    const float* s = (const float*)srcv;
#pragma unroll
    for (int j = 0; j < 8; ++j) tmp.v[j] = f2bf(s[(e0 + j) * HD_ + n]);
  }
  *(u32x4*)(wf + (size_t)t * 8) = *(const u32x4*)tmp.v;
}

// Projection from an LDS-staged weight slice: conflict-free b128 frag reads.
__device__ __forceinline__ void proj4_lds(const u16* __restrict__ Wb, int lane,
                                          const s16x8 xfrag[8], f32x4 acc[4]) {
  const u32x4* w4 = (const u32x4*)Wb + lane;
#pragma unroll
  for (int tc = 0; tc < 4; ++tc) acc[tc] = (f32x4){0.f, 0.f, 0.f, 0.f};
#pragma unroll
  for (int ks = 0; ks < 8; ++ks) {
#pragma unroll
    for (int tc = 0; tc < 4; ++tc) {
      u32x4 raw = w4[(ks * 4 + tc) * 64];
      s16x8 bfr = *(const s16x8*)&raw;
      acc[tc] = __builtin_amdgcn_mfma_f32_16x16x32_bf16(xfrag[ks], bfr, acc[tc], 0, 0, 0);
    }
  }
}

// Fallback (ws too small for WF): gather B-frags from the original layout.
__device__ __forceinline__ void proj4_direct(const void* __restrict__ srcv, bool isbf,
                                             int h, int lane, const s16x8 xfrag[8],
                                             f32x4 acc[4]) {
#pragma unroll
  for (int tc = 0; tc < 4; ++tc) acc[tc] = (f32x4){0.f, 0.f, 0.f, 0.f};
  int e8 = (lane >> 4) * 8;
  int nc = h * D_ + (lane & 15);
#pragma unroll
  for (int ks = 0; ks < 8; ++ks) {
#pragma unroll
    for (int tc = 0; tc < 4; ++tc) {
      U16x8 tmp;
      if (isbf) {
        const u16* s = (const u16*)srcv;
#pragma unroll
        for (int j = 0; j < 8; ++j) tmp.v[j] = s[(ks * 32 + e8 + j) * HD_ + nc + tc * 16];
      } else {
        const float* s = (const float*)srcv;
#pragma unroll
        for (int j = 0; j < 8; ++j) tmp.v[j] = f2bf(s[(ks * 32 + e8 + j) * HD_ + nc + tc * 16]);
      }
      s16x8 bfr = *(const s16x8*)tmp.v;
      acc[tc] = __builtin_amdgcn_mfma_f32_16x16x32_bf16(xfrag[ks], bfr, acc[tc], 0, 0, 0);
    }
  }
}

// Scatter projection C-frags (row=quad*4+r, col=tc*16+col) into A/B-frag-major
// LDS layout — same index formula for Q and K.
__device__ __forceinline__ void scatter_qk(u16* dst, int w, int quad, int col,
                                           const f32x4 acc[4]) {
#pragma unroll
  for (int tc = 0; tc < 4; ++tc) {
    int ks2 = tc >> 1;
    int q2  = (tc & 1) * 2 + (col >> 3);
#pragma unroll
    for (int r = 0; r < 4; ++r)
      dst[(((w * 2 + ks2) * 64) + q2 * 16 + quad * 4 + r) * 8 + (col & 7)] =
          f2bf(acc[tc][r]);
  }
}

// V goes to B-frag-major for O = P@V (k = s', n = d).
__device__ __forceinline__ void scatter_v(u16* Vf, int w, int quad, int col,
                                          const f32x4 acc[4]) {
#pragma unroll
  for (int tc = 0; tc < 4; ++tc)
#pragma unroll
    for (int r = 0; r < 4; ++r) {
      int srow = quad * 4 + r;
      int q2   = (w & 1) * 2 + (srow >> 3);
      Vf[((((w >> 1) * 4 + tc) * 64) + q2 * 16 + col) * 8 + (srow & 7)] =
          f2bf(acc[tc][r]);
    }
}

// ---------------------------------------------------------------------------
// Fused MHA, weight-LDS + head-pipelined. One workgroup per batch, 8 waves,
// 1 block/CU (144 KiB LDS).
// Per head h: 4 sub-phases (Q,K,V,R). Each sub-phase:
//   __syncthreads (drains last DMA)  ->  DMA next 32 KiB weight slice into
//   Wbuf[p^1]  ->  proj slice p from Wbuf[p&1] (ds_read_b128, conflict-free)
//   || one attn chunk of head h-1 (QK / softmax / P-exch+PV / epilogue).
// This cuts per-CU L2 weight traffic 8x (each block DMAs each slice once,
// 8 waves read it from LDS) — L2 streaming was ~half of round-3's time.
// LDS: Wbuf 2x32K | Qf 16K | Kf 2x16K | Vf 2x16K = 144 KiB.
// ---------------------------------------------------------------------------
__global__ __launch_bounds__(512) void mha_fused(
    const void* __restrict__ Xv, const u16* __restrict__ WF,
    const void* __restrict__ wqv, const void* __restrict__ wkv,
    const void* __restrict__ wvv, const void* __restrict__ wrv,
    void* __restrict__ outv, const u32* __restrict__ flag, int useWF) {
  __shared__ __align__(16) u16 smem[73728];   // 144 KiB
  u16* Wb0 = smem;               // 16384 u16 = 32 KiB
  u16* Wb1 = smem + 16384;
  u16* Qf  = smem + 32768;       // 8192
  u16* KfB = smem + 40960;       // 2 x 8192
  u16* VfB = smem + 57344;       // 2 x 8192

  const bool isbf = (flag[0] != 0u);
  const int tid  = threadIdx.x;
  const int w    = tid >> 6;     // wave id: owns rows [16w, 16w+16)
  const int lane = tid & 63;
  const int quad = lane >> 4;
  const int col  = lane & 15;
  const int b    = blockIdx.x;

  // ---- prologue DMA: slice (Q, head 0) -> Wb0 (flies under X staging) ----
  if (useWF) dma_w(WF, 0, Wb0, tid);

  // ---- stage X[b] through LDS (two halves) into per-wave A-frags ----
  // scratch = KfB region (32 KiB), untouched by the prologue DMA.
  s16x8 xfrag[8];
  {
    u32x4* xs = (u32x4*)KfB;
#pragma unroll
    for (int half = 0; half < 2; ++half) {
      int cbase = half * 2048;
#pragma unroll
      for (int k = 0; k < 4; ++k) {
        int c  = cbase + tid + k * 512;       // 8-element chunk id
        int s  = c >> 5;                      // row 0..127
        int e0 = (c & 31) * 8;                // elem base within row
        U16x8 tmp;
        if (isbf) {
          const u32x4* xg = (const u32x4*)Xv + (size_t)b * 4096;
          u32x4 raw = xg[c];
          tmp = *(const U16x8*)&raw;
        } else {
          const f32x4* xg = (const f32x4*)Xv + (size_t)b * 8192;
          f32x4 lo = xg[2 * c], hi = xg[2 * c + 1];
#pragma unroll
          for (int j = 0; j < 4; ++j) { tmp.v[j] = f2bf(lo[j]); tmp.v[4 + j] = f2bf(hi[j]); }
        }
        xs[(((s >> 4) & 3) * 8 + (e0 >> 5)) * 64 + ((e0 >> 3) & 3) * 16 + (s & 15)] =
            *(const u32x4*)tmp.v;
      }
      __syncthreads();
      if ((w >> 2) == half) {
        int trl = w & 3;
#pragma unroll
        for (int ks = 0; ks < 8; ++ks) {
          u32x4 raw = xs[(trl * 8 + ks) * 64 + lane];
          xfrag[ks] = *(const s16x8*)&raw;
        }
      }
      __syncthreads();
    }
  }

  s16x8 aq[2];      // QK^T B-frags (head in flight), register-carried
  f32x4 ra[4];      // residual C-frags (head in flight)

  const int sl0 = (lane & 15) | ((lane & 16) << 1);   // q + ((quad&1)?32:0)
  const bool hiq = (lane >= 32);                      // quad>>1

  for (int h = 0; h <= H_; ++h) {
    const int hp = h - 1;
    const u16* Kp = KfB + (hp & 1) * 8192;   // valid when h>0
    const u16* Vp = VfB + (hp & 1) * 8192;
    u16* Kc = KfB + (h & 1) * 8192;
    u16* Vc = VfB + (h & 1) * 8192;

    f32x4 sacc[8];
    u32 wp[8][2];
    f32x4 oacc[4];
    float linv = 0.f;
    s16x8 aqn[2];
    f32x4 acc[4];

    // ================= sub-phase 0: proj Q(h) || QK^T(h-1) =================
    __syncthreads();                                   // DMA(Q,h) landed
    if (useWF && h < H_) dma_w(WF, 8 + h, Wb1, tid);   // -> (K,h)
    if (h < H_) {
      if (useWF) proj4_lds(Wb0, lane, xfrag, acc);
      else       proj4_direct(wqv, isbf, h, lane, xfrag, acc);
      scatter_qk(Qf, w, quad, col, acc);
      aqn[0] = *(const s16x8*)(Qf + ((w * 2 + 0) * 64 + lane) * 8);
      aqn[1] = *(const s16x8*)(Qf + ((w * 2 + 1) * 64 + lane) * 8);
    }
    if (h > 0) {
      // S^T = K Q^T (swapped): lane holds P column-slice, 32 of 128 k.
#pragma unroll
      for (int tS = 0; tS < 8; ++tS) {
        sacc[tS] = (f32x4){0.f, 0.f, 0.f, 0.f};
#pragma unroll
        for (int k2 = 0; k2 < 2; ++k2) {
          s16x8 bk = *(const s16x8*)(Kp + ((tS * 2 + k2) * 64 + lane) * 8);
          sacc[tS] = __builtin_amdgcn_mfma_f32_16x16x32_bf16(bk, aq[k2], sacc[tS], 0, 0, 0);
        }
      }
    }
    if (h < H_) { aq[0] = aqn[0]; aq[1] = aqn[1]; }

    // ================= sub-phase 1: proj K(h) || softmax(h-1) ==============
    __syncthreads();                                   // DMA(K,h) landed
    if (useWF && h < H_) dma_w(WF, 16 + h, Wb0, tid);  // -> (V,h)
    if (h < H_) {
      if (useWF) proj4_lds(Wb1, lane, xfrag, acc);
      else       proj4_direct(wkv, isbf, h, lane, xfrag, acc);
      scatter_qk(Kc, w, quad, col, acc);
    }
    if (h > 0) {
      float m = sacc[0][0];
#pragma unroll
      for (int tS = 0; tS < 8; ++tS)
#pragma unroll
        for (int r = 0; r < 4; ++r) m = fmaxf(m, sacc[tS][r]);
      m = fmaxf(m, __shfl_xor(m, 16));
      m = fmaxf(m, __shfl_xor(m, 32));
      float lsum = 0.f;
#pragma unroll
      for (int tS = 0; tS < 8; ++tS)
#pragma unroll
        for (int r = 0; r < 4; ++r) {
          float e = __expf(sacc[tS][r] - m);
          sacc[tS][r] = e;
          lsum += e;
        }
      lsum += __shfl_xor(lsum, 16);
      lsum += __shfl_xor(lsum, 32);
      linv = 1.0f / lsum;
#pragma unroll
      for (int tS = 0; tS < 8; ++tS) {
        wp[tS][0] = cvtpk_bf16(sacc[tS][0], sacc[tS][1]);
        wp[tS][1] = cvtpk_bf16(sacc[tS][2], sacc[tS][3]);
      }
    }

    // ================= sub-phase 2: proj V(h) || P-exch + PV(h-1) ==========
    __syncthreads();                                   // DMA(V,h) landed
    if (useWF && h < H_) dma_w(WF, 24 + h, Wb1, tid);  // -> (R,h)
    if (h < H_) {
      if (useWF) proj4_lds(Wb0, lane, xfrag, acc);
      else       proj4_direct(wvv, isbf, h, lane, xfrag, acc);
      scatter_v(Vc, w, quad, col, acc);
    }
    if (h > 0) {
#pragma unroll
      for (int tc = 0; tc < 4; ++tc) oacc[tc] = (f32x4){0.f, 0.f, 0.f, 0.f};
#pragma unroll
      for (int kt = 0; kt < 4; ++kt) {
        int a00 = __shfl((int)wp[2 * kt][0],     sl0);
        int a01 = __shfl((int)wp[2 * kt][1],     sl0);
        int a10 = __shfl((int)wp[2 * kt + 1][0], sl0);
        int a11 = __shfl((int)wp[2 * kt + 1][1], sl0);
        int b00 = __shfl((int)wp[2 * kt][0],     sl0 + 16);
        int b01 = __shfl((int)wp[2 * kt][1],     sl0 + 16);
        int b10 = __shfl((int)wp[2 * kt + 1][0], sl0 + 16);
        int b11 = __shfl((int)wp[2 * kt + 1][1], sl0 + 16);
        u32x4 av;
        av[0] = (u32)(hiq ? a10 : a00);
        av[1] = (u32)(hiq ? a11 : a01);
        av[2] = (u32)(hiq ? b10 : b00);
        av[3] = (u32)(hiq ? b11 : b01);
        s16x8 ap = *(const s16x8*)&av;
#pragma unroll
        for (int tc = 0; tc < 4; ++tc) {
          s16x8 bv = *(const s16x8*)(Vp + ((kt * 4 + tc) * 64 + lane) * 8);
          oacc[tc] = __builtin_amdgcn_mfma_f32_16x16x32_bf16(ap, bv, oacc[tc], 0, 0, 0);
        }
      }
    }

    // ================= sub-phase 3: proj R(h) || epilogue(h-1) =============
    __syncthreads();                                   // DMA(R,h) landed
    if (useWF && h + 1 < H_) dma_w(WF, h + 1, Wb0, tid);  // -> (Q,h+1)
    if (h < H_) {
      if (useWF) proj4_lds(Wb1, lane, xfrag, acc);
      else       proj4_direct(wrv, isbf, h, lane, xfrag, acc);
    }
    if (h > 0) {
      float linv_e[4];
#pragma unroll
      for (int r = 0; r < 4; ++r) linv_e[r] = __shfl(linv, quad * 4 + r);
#pragma unroll
      for (int tc = 0; tc < 4; ++tc)
#pragma unroll
        for (int r = 0; r < 4; ++r) {
          float v = oacc[tc][r] * linv_e[r] + ra[tc][r];
          v = fmaxf(v, 0.f);
          int s = w * 16 + quad * 4 + r;
          size_t idx = ((size_t)b * S_ + s) * HD_ + hp * D_ + tc * 16 + col;
          if (isbf) ((u16*)outv)[idx] = f2bf(v);
          else      ((float*)outv)[idx] = v;
        }
    }
    if (h < H_) {
#pragma unroll
      for (int tc = 0; tc < 4; ++tc) ra[tc] = acc[tc];
    }
  }
}

extern "C" void kernel_launch(void* const* d_in, const int* in_sizes, int n_in,
                              void* d_out, int out_size, void* d_ws, size_t ws_size,
                              hipStream_t stream) {
  const void* X  = d_in[0];
  const void* wq = d_in[1];
  const void* wk = d_in[2];
  const void* wv = d_in[3];
  const void* wr = d_in[4];

  u32* flag = (u32*)d_ws;                       // 4 B flag at ws offset 0
  u16* wf   = (u16*)((char*)d_ws + 4096);       // 1 MiB fragment cache
  int useWF = (ws_size >= (size_t)(1u << 20) + 4096) ? 1 : 0;

  probe_dtype<<<dim3(1), dim3(256), 0, stream>>>((const u32*)X, flag);
  if (useWF)
    repack_w<<<dim3(256), dim3(256), 0, stream>>>(wq, wk, wv, wr, flag, wf);
  mha_fused<<<dim3(B_), dim3(512), 0, stream>>>(X, wf, wq, wk, wv, wr, d_out, flag, useWF);
}